// Round 8
// baseline (149.195 us; speedup 1.0000x reference)
//
#include <hip/hip_runtime.h>

typedef short bf16x8 __attribute__((ext_vector_type(8)));
typedef float f32x4 __attribute__((ext_vector_type(4)));

#define KDIM 256
#define BT 128
#define BK 64

__device__ __forceinline__ unsigned short f2bf(float f) {
  unsigned u = __float_as_uint(f);
  unsigned r = (u + 0x7fffu + ((u >> 16) & 1u)) >> 16;  // RNE
  return (unsigned short)r;
}
__device__ __forceinline__ float bf2f(unsigned short b) {
  return __uint_as_float(((unsigned)b) << 16);
}

__device__ __forceinline__ void async_cp16(const void* g, void* l) {
  __builtin_amdgcn_global_load_lds(
      (const __attribute__((address_space(1))) unsigned int*)g,
      (__attribute__((address_space(3))) unsigned int*)l, 16, 0, 0);
}

// Kernel 1: fp32 -> bf16 convert, row sq (of bf16-rounded vals), column sums,
// sum(sq). 256 blocks x 32 rows. (r0-verified body.)
__global__ __launch_bounds__(256) void mmd_stage(
    const float* __restrict__ src, const float* __restrict__ tgt, int ns,
    unsigned short* __restrict__ Tbf, float* __restrict__ sq,
    float* __restrict__ scol, float* __restrict__ sum_sq) {
  __shared__ float sp[256];
  __shared__ float rw[4];
  int t = threadIdx.x;
  int lane = t & 63, wave = t >> 6;
  sp[t] = 0.f;
  __syncthreads();
  int sub = t & 31;   // 8-elem group within row
  int rsel = t >> 5;  // row within 8-row group
  float colacc[8];
#pragma unroll
  for (int j = 0; j < 8; ++j) colacc[j] = 0.f;
  float tsq = 0.f;
#pragma unroll
  for (int it = 0; it < 4; ++it) {
    int r = blockIdx.x * 32 + it * 8 + rsel;
    const float* rp = (r < ns) ? (src + (size_t)r * KDIM)
                               : (tgt + (size_t)(r - ns) * KDIM);
    float4 v0 = *(const float4*)(rp + sub * 8);
    float4 v1 = *(const float4*)(rp + sub * 8 + 4);
    float vals[8] = {v0.x, v0.y, v0.z, v0.w, v1.x, v1.y, v1.z, v1.w};
    unsigned pk[4];
    float ssp = 0.f;
#pragma unroll
    for (int j = 0; j < 4; ++j) {
      unsigned short b0 = f2bf(vals[2 * j]);
      unsigned short b1 = f2bf(vals[2 * j + 1]);
      float x0 = bf2f(b0), x1 = bf2f(b1);
      pk[j] = (unsigned)b0 | ((unsigned)b1 << 16);
      ssp += x0 * x0 + x1 * x1;
      colacc[2 * j] += x0;
      colacc[2 * j + 1] += x1;
    }
    *(uint4*)(Tbf + (size_t)r * KDIM + sub * 8) =
        make_uint4(pk[0], pk[1], pk[2], pk[3]);
    tsq += ssp;
    float ss = ssp;
#pragma unroll
    for (int off = 16; off; off >>= 1) ss += __shfl_down(ss, off, 32);
    if (sub == 0) sq[r] = ss;
  }
#pragma unroll
  for (int j = 0; j < 8; ++j) atomicAdd(&sp[sub * 8 + j], colacc[j]);
#pragma unroll
  for (int off = 32; off; off >>= 1) tsq += __shfl_down(tsq, off, 64);
  if (lane == 0) rw[wave] = tsq;
  __syncthreads();
  atomicAdd(&scol[t], sp[t]);
  if (t == 0) atomicAdd(sum_sq, rw[0] + rw[1] + rw[2] + rw[3]);
}

__device__ __forceinline__ float2 pk_add(float2 a, float2 b) {
  return make_float2(a.x + b.x, a.y + b.y);
}
__device__ __forceinline__ float2 pk_mul(float2 a, float2 b) {
  return make_float2(a.x * b.x, a.y * b.y);
}
__device__ __forceinline__ float2 pk_fma(float2 a, float2 b, float2 c) {
  return make_float2(__builtin_fmaf(a.x, b.x, c.x),
                     __builtin_fmaf(a.y, b.y, c.y));
}

// Kernel 2: fused Gram-tile (MFMA) + L2 + 5-kernel sum + reduction.
// Body = r7's verified winner (107.7us; atomic hot-spot removed -> profiled
// main dropped below the fill floor). Two additions this round:
//  (a) XCD-aware tile-id swizzle (2080 % 8 == 0 -> simple bijective form):
//      co-XCD blocks get contiguous triangular ids -> shared row panels hit
//      the same per-XCD L2 (FETCH was ~5x the 4MB matrix).
//  (b) mmd_reduce fused in via non-blocking last-block election (release
//      partial store + agent-scope counter; last block grid-strides the
//      partials and plain-stores out[0], summation order identical to r7's
//      separate kernel) -> saves one launch + gap.
__global__ __launch_bounds__(256) void mmd_main(
    const unsigned short* __restrict__ Tbf, const float* __restrict__ sq,
    const float* __restrict__ scol, const float* __restrict__ sum_sq,
    float* __restrict__ partials, unsigned int* __restrict__ done,
    float* __restrict__ out, int n, int halfTiles, int nblk, float inv) {
  __shared__ short As[BT * BK];
  __shared__ short Bs[BT * BK];
  __shared__ float sqa[BT];
  __shared__ float sqb[BT];
  __shared__ float red[4];
  __shared__ float s_c4;
  __shared__ int s_last;

  // XCD swizzle: consecutive ids within one XCD's chunk of the triangle
  int id = ((int)blockIdx.x & 7) * (nblk >> 3) + ((int)blockIdx.x >> 3);
  int bi = (int)((sqrtf(8.f * (float)id + 1.f) - 1.f) * 0.5f);
  while ((bi + 1) * (bi + 2) / 2 <= id) ++bi;
  while (bi * (bi + 1) / 2 > id) --bi;
  int bj = id - bi * (bi + 1) / 2;
  int rowBase = bi * BT, colBase = bj * BT;

  int t = threadIdx.x;
  int lane = t & 63, wave = t >> 6;

  // fused coef (wave 0): c4 = -log2e/(16*bw). s_c4 ds_write drains at the
  // first __syncthreads; read only after the K-loop's barriers.
  if (wave == 0) {
    float4 v = *(const float4*)(scol + lane * 4);
    float p = v.x * v.x + v.y * v.y + v.z * v.z + v.w * v.w;
#pragma unroll
    for (int off = 32; off; off >>= 1) p += __shfl_down(p, off, 64);
    if (lane == 0) {
      double ssq = (double)p, S = (double)sum_sq[0], nn = (double)n;
      double bwv = (2.0 * nn * S - 2.0 * ssq) / (nn * nn - nn) / 4.0;
      s_c4 = (float)(-1.4426950408889634 / (bwv * 16.0));
    }
  }

  if (t < 128) sqa[t] = sq[rowBase + t];
  else sqb[t - 128] = sq[colBase + (t - 128)];

  f32x4 acc[4][4];
#pragma unroll
  for (int a = 0; a < 4; ++a)
#pragma unroll
    for (int b = 0; b < 4; ++b) {
      f32x4 z = {0.f, 0.f, 0.f, 0.f};
      acc[a][b] = z;
    }

  int wrow = (wave >> 1) * 64, wcol = (wave & 1) * 64;
  // staging: lane -> (row=lane/8, swizzled kgroup = (lane%8) ^ (lane/8))
  int lrow = lane >> 3;
  int kgsw = (lane & 7) ^ lrow;
  // ds_read: fragment row = lane&15, k-quad = lane>>4
  int frow = lane & 15;
  int kq = lane >> 4;

  for (int c = 0; c < 4; ++c) {
    int k0 = c * BK;
#pragma unroll
    for (int j = 0; j < 4; ++j) {
      int R0 = j * 32 + wave * 8;
      int ldsoff = (j * 256 + wave * 64) * 8;  // shorts; HW adds lane*16B
      async_cp16(Tbf + (size_t)(rowBase + R0 + lrow) * KDIM + k0 + kgsw * 8,
                 &As[ldsoff]);
      async_cp16(Tbf + (size_t)(colBase + R0 + lrow) * KDIM + k0 + kgsw * 8,
                 &Bs[ldsoff]);
    }
    __syncthreads();
#pragma unroll
    for (int ks = 0; ks < 2; ++ks) {
      bf16x8 af[4], bfv[4];
#pragma unroll
      for (int mt = 0; mt < 4; ++mt) {
        int r = wrow + mt * 16 + frow;
        int pg = (ks * 4 + kq) ^ (r & 7);  // undo XOR swizzle
        af[mt] = *(const bf16x8*)&As[r * BK + pg * 8];
      }
#pragma unroll
      for (int nt = 0; nt < 4; ++nt) {
        int r = wcol + nt * 16 + frow;
        int pg = (ks * 4 + kq) ^ (r & 7);
        bfv[nt] = *(const bf16x8*)&Bs[r * BK + pg * 8];
      }
#pragma unroll
      for (int mt = 0; mt < 4; ++mt)
#pragma unroll
        for (int nt = 0; nt < 4; ++nt)
          acc[mt][nt] = __builtin_amdgcn_mfma_f32_16x16x32_bf16(
              af[mt], bfv[nt], acc[mt][nt], 0, 0, 0);
    }
    __syncthreads();
  }

  // epilogue: C/D layout col=lane&15, row=(lane>>4)*4+reg  [m89]
  float c4 = s_c4;
  float m2c4 = -2.f * c4;
  float2 m2v = make_float2(m2c4, m2c4);
  int ccol = lane & 15;
  int rb = (lane >> 4) * 4;
  float ra[16];
#pragma unroll
  for (int mt = 0; mt < 4; ++mt)
#pragma unroll
    for (int rg = 0; rg < 4; ++rg)
      ra[mt * 4 + rg] = sqa[wrow + mt * 16 + rb + rg] * c4;
  float cbv[4];
#pragma unroll
  for (int nt = 0; nt < 4; ++nt) cbv[nt] = sqb[wcol + nt * 16 + ccol] * c4;

  float2 lsum2 = make_float2(0.f, 0.f);
#pragma unroll
  for (int mt = 0; mt < 4; ++mt) {
#pragma unroll
    for (int nt = 0; nt < 4; ++nt) {
      float cb = cbv[nt];
#pragma unroll
      for (int rp = 0; rp < 4; rp += 2) {
        float2 g = make_float2(acc[mt][nt][rp], acc[mt][nt][rp + 1]);
        float2 sab = make_float2(ra[mt * 4 + rp] + cb, ra[mt * 4 + rp + 1] + cb);
        float2 u = pk_fma(g, m2v, sab);
        float2 e = make_float2(__builtin_amdgcn_exp2f(u.x),
                               __builtin_amdgcn_exp2f(u.y));
        float2 e2 = pk_mul(e, e);
        float2 e4 = pk_mul(e2, e2);
        float2 e8 = pk_mul(e4, e4);
        float2 s = pk_add(e, e2);
        s = pk_add(s, e4);
        s = pk_add(s, e8);
        s = pk_fma(e8, e8, s);  // + e^16
        lsum2 = pk_add(lsum2, s);
      }
    }
  }
  float lsum = lsum2.x + lsum2.y;
#pragma unroll
  for (int off = 32; off; off >>= 1) lsum += __shfl_down(lsum, off, 64);
  if (lane == 0) red[wave] = lsum;
  __syncthreads();

  // per-block partial (distinct addresses — no same-address atomic), then
  // non-blocking last-block election; last block reduces and stores out[0].
  if (t == 0) {
    float w = ((bi < halfTiles) == (bj < halfTiles)) ? 1.f : -1.f;
    float f = (bi == bj) ? 1.f : 2.f;
    float val = w * f * inv * (red[0] + red[1] + red[2] + red[3]);
    __hip_atomic_store(&partials[id], val, __ATOMIC_RELEASE,
                       __HIP_MEMORY_SCOPE_AGENT);
    unsigned int old = __hip_atomic_fetch_add(done, 1u, __ATOMIC_ACQ_REL,
                                              __HIP_MEMORY_SCOPE_AGENT);
    s_last = (old == (unsigned)(nblk - 1));
  }
  __syncthreads();  // broadcast s_last; orders threads after t0's acquire

  if (s_last) {
    float a2 = 0.f;
    for (int j = t; j < nblk; j += 256)  // same order as r7's mmd_reduce
      a2 += __hip_atomic_load(&partials[j], __ATOMIC_RELAXED,
                              __HIP_MEMORY_SCOPE_AGENT);
#pragma unroll
    for (int off = 32; off; off >>= 1) a2 += __shfl_down(a2, off, 64);
    if (lane == 0) red[wave] = a2;
    __syncthreads();
    if (t == 0) out[0] = red[0] + red[1] + red[2] + red[3];
  }
}

extern "C" void kernel_launch(void* const* d_in, const int* in_sizes, int n_in,
                              void* d_out, int out_size, void* d_ws,
                              size_t ws_size, hipStream_t stream) {
  const float* src = (const float*)d_in[0];
  const float* tgt = (const float*)d_in[1];
  int ns = in_sizes[0] / KDIM;   // 4096
  int ntr = in_sizes[1] / KDIM;  // 4096
  int n = ns + ntr;              // 8192

  char* ws = (char*)d_ws;
  unsigned short* Tbf = (unsigned short*)ws;  // 4 MiB bf16 matrix
  size_t off = (size_t)n * KDIM * sizeof(unsigned short);
  float* sq = (float*)(ws + off);          off += (size_t)n * 4;
  float* scol = (float*)(ws + off);        off += (size_t)KDIM * 4;
  float* sum_sq = (float*)(ws + off);      off += 4;
  unsigned int* done = (unsigned int*)(ws + off); off += 4;
  float* partials = (float*)(ws + off);

  // zero scol + sum_sq + done counter (ws is poisoned 0xAA before every call)
  hipMemsetAsync(scol, 0, (KDIM + 2) * sizeof(float), stream);

  mmd_stage<<<n / 32, 256, 0, stream>>>(src, tgt, ns, Tbf, sq, scol, sum_sq);

  int nb = n / BT;               // 64
  int nblk = nb * (nb + 1) / 2;  // 2080 (divisible by 8 -> bijective swizzle)
  mmd_main<<<nblk, 256, 0, stream>>>(Tbf, sq, scol, sum_sq, partials, done,
                                     (float*)d_out, n, ns / BT, nblk,
                                     1.f / ((float)ns * (float)ns));
}

// Round 9
// 107.333 us; speedup vs baseline: 1.3900x; 1.3900x over previous
//
#include <hip/hip_runtime.h>

typedef short bf16x8 __attribute__((ext_vector_type(8)));
typedef float f32x4 __attribute__((ext_vector_type(4)));

#define KDIM 256
#define BT 128
#define BK 64

__device__ __forceinline__ unsigned short f2bf(float f) {
  unsigned u = __float_as_uint(f);
  unsigned r = (u + 0x7fffu + ((u >> 16) & 1u)) >> 16;  // RNE
  return (unsigned short)r;
}
__device__ __forceinline__ float bf2f(unsigned short b) {
  return __uint_as_float(((unsigned)b) << 16);
}

__device__ __forceinline__ void async_cp16(const void* g, void* l) {
  __builtin_amdgcn_global_load_lds(
      (const __attribute__((address_space(1))) unsigned int*)g,
      (__attribute__((address_space(3))) unsigned int*)l, 16, 0, 0);
}

// Kernel 1: fp32 -> bf16 convert, row sq (of bf16-rounded vals), column sums,
// sum(sq). 256 blocks x 32 rows. (r0-verified body.)
__global__ __launch_bounds__(256) void mmd_stage(
    const float* __restrict__ src, const float* __restrict__ tgt, int ns,
    unsigned short* __restrict__ Tbf, float* __restrict__ sq,
    float* __restrict__ scol, float* __restrict__ sum_sq) {
  __shared__ float sp[256];
  __shared__ float rw[4];
  int t = threadIdx.x;
  int lane = t & 63, wave = t >> 6;
  sp[t] = 0.f;
  __syncthreads();
  int sub = t & 31;   // 8-elem group within row
  int rsel = t >> 5;  // row within 8-row group
  float colacc[8];
#pragma unroll
  for (int j = 0; j < 8; ++j) colacc[j] = 0.f;
  float tsq = 0.f;
#pragma unroll
  for (int it = 0; it < 4; ++it) {
    int r = blockIdx.x * 32 + it * 8 + rsel;
    const float* rp = (r < ns) ? (src + (size_t)r * KDIM)
                               : (tgt + (size_t)(r - ns) * KDIM);
    float4 v0 = *(const float4*)(rp + sub * 8);
    float4 v1 = *(const float4*)(rp + sub * 8 + 4);
    float vals[8] = {v0.x, v0.y, v0.z, v0.w, v1.x, v1.y, v1.z, v1.w};
    unsigned pk[4];
    float ssp = 0.f;
#pragma unroll
    for (int j = 0; j < 4; ++j) {
      unsigned short b0 = f2bf(vals[2 * j]);
      unsigned short b1 = f2bf(vals[2 * j + 1]);
      float x0 = bf2f(b0), x1 = bf2f(b1);
      pk[j] = (unsigned)b0 | ((unsigned)b1 << 16);
      ssp += x0 * x0 + x1 * x1;
      colacc[2 * j] += x0;
      colacc[2 * j + 1] += x1;
    }
    *(uint4*)(Tbf + (size_t)r * KDIM + sub * 8) =
        make_uint4(pk[0], pk[1], pk[2], pk[3]);
    tsq += ssp;
    float ss = ssp;
#pragma unroll
    for (int off = 16; off; off >>= 1) ss += __shfl_down(ss, off, 32);
    if (sub == 0) sq[r] = ss;
  }
#pragma unroll
  for (int j = 0; j < 8; ++j) atomicAdd(&sp[sub * 8 + j], colacc[j]);
#pragma unroll
  for (int off = 32; off; off >>= 1) tsq += __shfl_down(tsq, off, 64);
  if (lane == 0) rw[wave] = tsq;
  __syncthreads();
  atomicAdd(&scol[t], sp[t]);
  if (t == 0) atomicAdd(sum_sq, rw[0] + rw[1] + rw[2] + rw[3]);
}

__device__ __forceinline__ float2 pk_add(float2 a, float2 b) {
  return make_float2(a.x + b.x, a.y + b.y);
}
__device__ __forceinline__ float2 pk_mul(float2 a, float2 b) {
  return make_float2(a.x * b.x, a.y * b.y);
}
__device__ __forceinline__ float2 pk_fma(float2 a, float2 b, float2 c) {
  return make_float2(__builtin_fmaf(a.x, b.x, c.x),
                     __builtin_fmaf(a.y, b.y, c.y));
}

// Kernel 2: fused Gram-tile (MFMA) + L2 + 5-kernel sum + block reduction.
// Body = r7's verified winner (107.7us) + ONE r8 component kept: the XCD
// tile-id swizzle. r8's counters exonerated the swizzle (FETCH 17-21MB ->
// 12.3MB as predicted) and convicted the fused last-block election (2080
// BLOCKING same-address ACQ_REL fetch_adds -> main 80us). Election removed;
// plain per-block partial store + separate mmd_reduce kernel restored.
// NO cross-block atomics/loops of any kind in this kernel.
__global__ __launch_bounds__(256) void mmd_main(
    const unsigned short* __restrict__ Tbf, const float* __restrict__ sq,
    const float* __restrict__ scol, const float* __restrict__ sum_sq,
    float* __restrict__ partials, int n, int halfTiles, int nblk, float inv) {
  __shared__ short As[BT * BK];
  __shared__ short Bs[BT * BK];
  __shared__ float sqa[BT];
  __shared__ float sqb[BT];
  __shared__ float red[4];
  __shared__ float s_c4;

  // XCD swizzle (bijective: nblk % 8 == 0): consecutive triangular ids land
  // on the same XCD -> shared row panels hit the same per-XCD L2.
  int id = ((int)blockIdx.x & 7) * (nblk >> 3) + ((int)blockIdx.x >> 3);
  int bi = (int)((sqrtf(8.f * (float)id + 1.f) - 1.f) * 0.5f);
  while ((bi + 1) * (bi + 2) / 2 <= id) ++bi;
  while (bi * (bi + 1) / 2 > id) --bi;
  int bj = id - bi * (bi + 1) / 2;
  int rowBase = bi * BT, colBase = bj * BT;

  int t = threadIdx.x;
  int lane = t & 63, wave = t >> 6;

  // fused coef (wave 0): c4 = -log2e/(16*bw). s_c4 ds_write drains at the
  // first __syncthreads; read only after the K-loop's barriers.
  if (wave == 0) {
    float4 v = *(const float4*)(scol + lane * 4);
    float p = v.x * v.x + v.y * v.y + v.z * v.z + v.w * v.w;
#pragma unroll
    for (int off = 32; off; off >>= 1) p += __shfl_down(p, off, 64);
    if (lane == 0) {
      double ssq = (double)p, S = (double)sum_sq[0], nn = (double)n;
      double bwv = (2.0 * nn * S - 2.0 * ssq) / (nn * nn - nn) / 4.0;
      s_c4 = (float)(-1.4426950408889634 / (bwv * 16.0));
    }
  }

  if (t < 128) sqa[t] = sq[rowBase + t];
  else sqb[t - 128] = sq[colBase + (t - 128)];

  f32x4 acc[4][4];
#pragma unroll
  for (int a = 0; a < 4; ++a)
#pragma unroll
    for (int b = 0; b < 4; ++b) {
      f32x4 z = {0.f, 0.f, 0.f, 0.f};
      acc[a][b] = z;
    }

  int wrow = (wave >> 1) * 64, wcol = (wave & 1) * 64;
  // staging: lane -> (row=lane/8, swizzled kgroup = (lane%8) ^ (lane/8))
  int lrow = lane >> 3;
  int kgsw = (lane & 7) ^ lrow;
  // ds_read: fragment row = lane&15, k-quad = lane>>4
  int frow = lane & 15;
  int kq = lane >> 4;

  for (int c = 0; c < 4; ++c) {
    int k0 = c * BK;
#pragma unroll
    for (int j = 0; j < 4; ++j) {
      int R0 = j * 32 + wave * 8;
      int ldsoff = (j * 256 + wave * 64) * 8;  // shorts; HW adds lane*16B
      async_cp16(Tbf + (size_t)(rowBase + R0 + lrow) * KDIM + k0 + kgsw * 8,
                 &As[ldsoff]);
      async_cp16(Tbf + (size_t)(colBase + R0 + lrow) * KDIM + k0 + kgsw * 8,
                 &Bs[ldsoff]);
    }
    __syncthreads();
#pragma unroll
    for (int ks = 0; ks < 2; ++ks) {
      bf16x8 af[4], bfv[4];
#pragma unroll
      for (int mt = 0; mt < 4; ++mt) {
        int r = wrow + mt * 16 + frow;
        int pg = (ks * 4 + kq) ^ (r & 7);  // undo XOR swizzle
        af[mt] = *(const bf16x8*)&As[r * BK + pg * 8];
      }
#pragma unroll
      for (int nt = 0; nt < 4; ++nt) {
        int r = wcol + nt * 16 + frow;
        int pg = (ks * 4 + kq) ^ (r & 7);
        bfv[nt] = *(const bf16x8*)&Bs[r * BK + pg * 8];
      }
#pragma unroll
      for (int mt = 0; mt < 4; ++mt)
#pragma unroll
        for (int nt = 0; nt < 4; ++nt)
          acc[mt][nt] = __builtin_amdgcn_mfma_f32_16x16x32_bf16(
              af[mt], bfv[nt], acc[mt][nt], 0, 0, 0);
    }
    __syncthreads();
  }

  // epilogue: C/D layout col=lane&15, row=(lane>>4)*4+reg  [m89]
  float c4 = s_c4;
  float m2c4 = -2.f * c4;
  float2 m2v = make_float2(m2c4, m2c4);
  int ccol = lane & 15;
  int rb = (lane >> 4) * 4;
  float ra[16];
#pragma unroll
  for (int mt = 0; mt < 4; ++mt)
#pragma unroll
    for (int rg = 0; rg < 4; ++rg)
      ra[mt * 4 + rg] = sqa[wrow + mt * 16 + rb + rg] * c4;
  float cbv[4];
#pragma unroll
  for (int nt = 0; nt < 4; ++nt) cbv[nt] = sqb[wcol + nt * 16 + ccol] * c4;

  float2 lsum2 = make_float2(0.f, 0.f);
#pragma unroll
  for (int mt = 0; mt < 4; ++mt) {
#pragma unroll
    for (int nt = 0; nt < 4; ++nt) {
      float cb = cbv[nt];
#pragma unroll
      for (int rp = 0; rp < 4; rp += 2) {
        float2 g = make_float2(acc[mt][nt][rp], acc[mt][nt][rp + 1]);
        float2 sab = make_float2(ra[mt * 4 + rp] + cb, ra[mt * 4 + rp + 1] + cb);
        float2 u = pk_fma(g, m2v, sab);
        float2 e = make_float2(__builtin_amdgcn_exp2f(u.x),
                               __builtin_amdgcn_exp2f(u.y));
        float2 e2 = pk_mul(e, e);
        float2 e4 = pk_mul(e2, e2);
        float2 e8 = pk_mul(e4, e4);
        float2 s = pk_add(e, e2);
        s = pk_add(s, e4);
        s = pk_add(s, e8);
        s = pk_fma(e8, e8, s);  // + e^16
        lsum2 = pk_add(lsum2, s);
      }
    }
  }
  float lsum = lsum2.x + lsum2.y;
#pragma unroll
  for (int off = 32; off; off >>= 1) lsum += __shfl_down(lsum, off, 64);
  if (lane == 0) red[wave] = lsum;
  __syncthreads();
  if (t == 0) {
    float w = ((bi < halfTiles) == (bj < halfTiles)) ? 1.f : -1.f;
    float f = (bi == bj) ? 1.f : 2.f;
    partials[id] = w * f * inv * (red[0] + red[1] + red[2] + red[3]);
  }
}

// Kernel 3: reduce 2080 partials -> out[0]. One block, ~2 us. (r7-verified.)
__global__ __launch_bounds__(256) void mmd_reduce(
    const float* __restrict__ partials, int nblk, float* __restrict__ out) {
  __shared__ float red[4];
  int t = threadIdx.x;
  int lane = t & 63, wave = t >> 6;
  float a = 0.f;
  for (int j = t; j < nblk; j += 256) a += partials[j];
#pragma unroll
  for (int off = 32; off; off >>= 1) a += __shfl_down(a, off, 64);
  if (lane == 0) red[wave] = a;
  __syncthreads();
  if (t == 0) out[0] = red[0] + red[1] + red[2] + red[3];
}

extern "C" void kernel_launch(void* const* d_in, const int* in_sizes, int n_in,
                              void* d_out, int out_size, void* d_ws,
                              size_t ws_size, hipStream_t stream) {
  const float* src = (const float*)d_in[0];
  const float* tgt = (const float*)d_in[1];
  int ns = in_sizes[0] / KDIM;   // 4096
  int ntr = in_sizes[1] / KDIM;  // 4096
  int n = ns + ntr;              // 8192

  char* ws = (char*)d_ws;
  unsigned short* Tbf = (unsigned short*)ws;  // 4 MiB bf16 matrix
  size_t off = (size_t)n * KDIM * sizeof(unsigned short);
  float* sq = (float*)(ws + off);       off += (size_t)n * 4;
  float* scol = (float*)(ws + off);     off += (size_t)KDIM * 4;
  float* sum_sq = (float*)(ws + off);   off += 4;
  float* partials = (float*)(ws + off);

  // zero scol + sum_sq (ws is poisoned 0xAA before every call)
  hipMemsetAsync(scol, 0, (KDIM + 1) * sizeof(float), stream);

  mmd_stage<<<n / 32, 256, 0, stream>>>(src, tgt, ns, Tbf, sq, scol, sum_sq);

  int nb = n / BT;               // 64
  int nblk = nb * (nb + 1) / 2;  // 2080 (divisible by 8 -> bijective swizzle)
  mmd_main<<<nblk, 256, 0, stream>>>(Tbf, sq, scol, sum_sq, partials, n,
                                     ns / BT, nblk,
                                     1.f / ((float)ns * (float)ns));
  mmd_reduce<<<1, 256, 0, stream>>>(partials, nblk, (float*)d_out);
}